// Round 10
// baseline (99.259 us; speedup 1.0000x reference)
//
#include <hip/hip_runtime.h>

// x     [B=32, I=64, K=8192]        f32
// U_in  [I=64, R=8,  K=8192, H=4]   f32  -> float4 per (i,r,k)
// M     [R=8,  S=8,  K=8192, H=4]   f32
// U_out [O=64, S=8,  K=8192, H=4]   f32
// out   [B=32, O=64, K=8192]        f32
//
// Round 10 = R5 geometry (512 thr = 16 kk x 32 b, 1 b/thread, grid 512,
// R=4 LDS ring, 1 barrier/phase, counted vmcnt, VGPR pinned 64 via (512,4)
// -> 16 waves/CU) + permlane32_swap weight pairing:
//   lanes 0-31 (b&2==0) ds_read row 2rp, lanes 32-63 read row 2rp+1 of each
//   pair; v_permlane32_swap_b32(w,w) returns {row2rp on all lanes, row2rp+1
//   on all lanes} (paired lanes share kk; weights are b-independent).
//   1 ds_read_b128 + 4 VALU swaps replaces 2 ds_read_b128 in all 3 stages
//   -> LDS return bytes halve (R5's measured roofline), VALU x1.5 (headroom).
// Accumulators unchanged -> VGPR demand stays ~64.

static constexpr int IN_CH  = 64;
static constexpr int OUT_CH = 64;
static constexpr int RANK   = 8;
static constexpr int MODES  = 8192;
static constexpr int KT     = 16;            // k per block
static constexpr int CROWS  = 64;            // rows per chunk
static constexpr int CF4    = CROWS * KT;    // 1024 float4 = 16 KB per chunk

typedef const __attribute__((address_space(1))) void* gas_t;
typedef __attribute__((address_space(3))) void* las_t;
typedef int i32x2 __attribute__((ext_vector_type(2)));

#define FENCE asm volatile("" ::: "memory")

// E = row-pair even weight (read by lanes<32), O = odd (lanes>=32), both
// broadcast to all 64 lanes by the swap. Consumed per-component to keep
// live temps ~2 regs.
__device__ __forceinline__ void pair_fma_s(float4& aE, float4& aO,
                                           const float4 w, const float v) {
    i32x2 t;
    t = __builtin_amdgcn_permlane32_swap(__float_as_int(w.x), __float_as_int(w.x), false, false);
    aE.x = fmaf(__int_as_float(t.x), v, aE.x);
    aO.x = fmaf(__int_as_float(t.y), v, aO.x);
    t = __builtin_amdgcn_permlane32_swap(__float_as_int(w.y), __float_as_int(w.y), false, false);
    aE.y = fmaf(__int_as_float(t.x), v, aE.y);
    aO.y = fmaf(__int_as_float(t.y), v, aO.y);
    t = __builtin_amdgcn_permlane32_swap(__float_as_int(w.z), __float_as_int(w.z), false, false);
    aE.z = fmaf(__int_as_float(t.x), v, aE.z);
    aO.z = fmaf(__int_as_float(t.y), v, aO.z);
    t = __builtin_amdgcn_permlane32_swap(__float_as_int(w.w), __float_as_int(w.w), false, false);
    aE.w = fmaf(__int_as_float(t.x), v, aE.w);
    aO.w = fmaf(__int_as_float(t.y), v, aO.w);
}

// aE += E(w) .* v ; aO += O(w) .* v   (stage 2: two s-columns, same r-vector)
__device__ __forceinline__ void pair_fma_v(float4& aE, float4& aO,
                                           const float4 w, const float4 v) {
    i32x2 t;
    t = __builtin_amdgcn_permlane32_swap(__float_as_int(w.x), __float_as_int(w.x), false, false);
    aE.x = fmaf(__int_as_float(t.x), v.x, aE.x);
    aO.x = fmaf(__int_as_float(t.y), v.x, aO.x);
    t = __builtin_amdgcn_permlane32_swap(__float_as_int(w.y), __float_as_int(w.y), false, false);
    aE.y = fmaf(__int_as_float(t.x), v.y, aE.y);
    aO.y = fmaf(__int_as_float(t.y), v.y, aO.y);
    t = __builtin_amdgcn_permlane32_swap(__float_as_int(w.z), __float_as_int(w.z), false, false);
    aE.z = fmaf(__int_as_float(t.x), v.z, aE.z);
    aO.z = fmaf(__int_as_float(t.y), v.z, aO.z);
    t = __builtin_amdgcn_permlane32_swap(__float_as_int(w.w), __float_as_int(w.w), false, false);
    aE.w = fmaf(__int_as_float(t.x), v.w, aE.w);
    aO.w = fmaf(__int_as_float(t.y), v.w, aO.w);
}

// a += E(w) .* vE + O(w) .* vO   (stage 3: two s-terms into one o-acc)
__device__ __forceinline__ void pair_dot(float4& a, const float4 w,
                                         const float4 vE, const float4 vO) {
    i32x2 t;
    t = __builtin_amdgcn_permlane32_swap(__float_as_int(w.x), __float_as_int(w.x), false, false);
    a.x = fmaf(__int_as_float(t.x), vE.x, a.x);
    a.x = fmaf(__int_as_float(t.y), vO.x, a.x);
    t = __builtin_amdgcn_permlane32_swap(__float_as_int(w.y), __float_as_int(w.y), false, false);
    a.y = fmaf(__int_as_float(t.x), vE.y, a.y);
    a.y = fmaf(__int_as_float(t.y), vO.y, a.y);
    t = __builtin_amdgcn_permlane32_swap(__float_as_int(w.z), __float_as_int(w.z), false, false);
    a.z = fmaf(__int_as_float(t.x), vE.z, a.z);
    a.z = fmaf(__int_as_float(t.y), vO.z, a.z);
    t = __builtin_amdgcn_permlane32_swap(__float_as_int(w.w), __float_as_int(w.w), false, false);
    a.w = fmaf(__int_as_float(t.x), vE.w, a.w);
    a.w = fmaf(__int_as_float(t.y), vO.w, a.w);
}

// 8-wave staging: wave w loads rows [8w, 8w+8) of a [64 rows][16 kk] float4
// chunk with 2 global_load_lds_dwordx4 (1 KB each; wave-uniform LDS base).
__device__ __forceinline__ void stage_chunk8(const float4* gbase, float4* lbuf,
                                             int wid, int lane) {
    const int sub = lane >> 4;       // 0..3 row within quad
    const int col = lane & 15;       // 0..15 kk
#pragma unroll
    for (int j = 0; j < 2; ++j) {
        const int row0 = wid * 8 + j * 4;                        // wave-uniform
        const float4* src = gbase + (size_t)(row0 + sub) * MODES + col;
        float4* dst = lbuf + row0 * KT;                          // wave-uniform
        __builtin_amdgcn_global_load_lds((gas_t)src, (las_t)dst, 16, 0, 0);
    }
}

__global__ __launch_bounds__(512, 4) void diag_lr_fused(
    const float*  __restrict__ x,
    const float4* __restrict__ Uin,
    const float4* __restrict__ Mw,
    const float4* __restrict__ Uout,
    float*        __restrict__ out)
{
    __shared__ float4 lds[4][CF4];   // 64 KB ring

    const int t    = threadIdx.x;
    const int kk   = t & 15;
    const int b    = t >> 4;         // 0..31 (one b per thread)
    const int lane = t & 63;
    const int wid  = t >> 6;         // 0..7
    const int hbit = (t >> 5) & 1;   // lane bit5: 0 = E-reader, 1 = O-reader
    const int k0   = blockIdx.x * KT;
    const int k    = k0 + kk;

    const float4* UinB = Uin  + k0;  // row p -> + p*MODES
    const float4* MB   = Mw   + k0;
    const float4* UoB  = Uout + k0;
    const float*  xp = x   + (size_t)b * (IN_CH  * MODES) + k;
    float*        op = out + (size_t)b * (OUT_CH * MODES) + k;

#define CHUNK_PTR(cc) ((cc) < 8 ? (UinB + (size_t)(cc) * CROWS * MODES) \
                     : (cc) == 8 ? MB \
                     : (UoB + (size_t)((cc) - 9) * CROWS * MODES))

    float xa[2][8];                  // x double buffer, static indices only

    // ---- prologue: queue order [s0(2), x0(8), s1(2)] ----
    stage_chunk8(CHUNK_PTR(0), &lds[0][0], wid, lane);
    FENCE;
#pragma unroll
    for (int ii = 0; ii < 8; ++ii) xa[0][ii] = xp[ii * MODES];
    FENCE;
    stage_chunk8(CHUNK_PTR(1), &lds[1][0], wid, lane);
    FENCE;

    float4 racc[RANK];
#pragma unroll
    for (int r = 0; r < RANK; ++r) racc[r] = make_float4(0.f, 0.f, 0.f, 0.f);

    // ---- phases 0..7: U_in (rows ii*8+r; pair over r) ----
#pragma unroll
    for (int c = 0; c < 8; ++c) {
        asm volatile("s_waitcnt vmcnt(2)" ::: "memory");  // s(c), x(c) landed
        __builtin_amdgcn_s_barrier();
        FENCE;
        if (c < 7) {                                      // x(c+1) first,
#pragma unroll
            for (int ii = 0; ii < 8; ++ii)
                xa[(c + 1) & 1][ii] = xp[((c + 1) * 8 + ii) * MODES];
            FENCE;
        }
        stage_chunk8(CHUNK_PTR(c + 2), &lds[(c + 2) & 3][0], wid, lane); // then stage
        FENCE;
        const float4* Lb = &lds[c & 3][0];
#pragma unroll
        for (int ii = 0; ii < 8; ++ii) {
            const float xv = xa[c & 1][ii];
#pragma unroll
            for (int rp = 0; rp < 4; ++rp) {
                const float4 w = Lb[(ii * 8 + 2 * rp + hbit) * KT + kk];
                pair_fma_s(racc[2 * rp], racc[2 * rp + 1], w, xv);
            }
        }
        FENCE;
    }

    // ---- phase 8: M (lds[0]); rows r*8+s, pair over s ----
    float4 sacc[RANK];
#pragma unroll
    for (int s = 0; s < RANK; ++s) sacc[s] = make_float4(0.f, 0.f, 0.f, 0.f);
    {
        asm volatile("s_waitcnt vmcnt(2)" ::: "memory");  // s8 landed, keep s9
        __builtin_amdgcn_s_barrier();
        FENCE;
        stage_chunk8(CHUNK_PTR(10), &lds[10 & 3][0], wid, lane);
        FENCE;
        const float4* Lb = &lds[8 & 3][0];
#pragma unroll
        for (int r = 0; r < RANK; ++r)
#pragma unroll
            for (int sp = 0; sp < 4; ++sp) {
                const float4 w = Lb[(r * 8 + 2 * sp + hbit) * KT + kk];
                pair_fma_v(sacc[2 * sp], sacc[2 * sp + 1], w, racc[r]);
            }
        FENCE;
    }

    // ---- phases 9..16: U_out (rows oo*8+s, pair over s) ----
#pragma unroll
    for (int c = 9; c < 17; ++c) {
        // queue at wait (instr units): ph9 [s9,s10]->keep 2; ph10 [s10,s11,st9]
        // ->keep 10; ph11-15 [s(c),st(c-2),s(c+1),st(c-1)]->keep 18;
        // ph16 [st13,s16,st14,st15]->keep 16.   (stores = 8/phase)
        if      (c == 9)  asm volatile("s_waitcnt vmcnt(2)"  ::: "memory");
        else if (c == 10) asm volatile("s_waitcnt vmcnt(10)" ::: "memory");
        else if (c == 16) asm volatile("s_waitcnt vmcnt(16)" ::: "memory");
        else              asm volatile("s_waitcnt vmcnt(18)" ::: "memory");
        __builtin_amdgcn_s_barrier();
        FENCE;
        if (c + 2 <= 16) {
            stage_chunk8(CHUNK_PTR(c + 2), &lds[(c + 2) & 3][0], wid, lane);
            FENCE;
        }
        const float4* Lb = &lds[c & 3][0];
        const int oc = c - 9;
#pragma unroll
        for (int oo = 0; oo < 8; ++oo) {
            float4 a = make_float4(0.f, 0.f, 0.f, 0.f);
#pragma unroll
            for (int sp = 0; sp < 4; ++sp) {
                const float4 w = Lb[(oo * 8 + 2 * sp + hbit) * KT + kk];
                pair_dot(a, w, sacc[2 * sp], sacc[2 * sp + 1]);
            }
            op[(oc * 8 + oo) * MODES] = (a.x + a.y) + (a.z + a.w);
        }
        FENCE;
    }
#undef CHUNK_PTR
}

extern "C" void kernel_launch(void* const* d_in, const int* in_sizes, int n_in,
                              void* d_out, int out_size, void* d_ws, size_t ws_size,
                              hipStream_t stream) {
    const float*  x    = (const float*)d_in[0];
    const float4* Uin  = (const float4*)d_in[1];
    const float4* Mw   = (const float4*)d_in[2];
    const float4* Uout = (const float4*)d_in[3];
    float* out = (float*)d_out;

    dim3 grid(512), block(512);
    hipLaunchKernelGGL(diag_lr_fused, grid, block, 0, stream, x, Uin, Mw, Uout, out);
}

// Round 11
// 94.108 us; speedup vs baseline: 1.0547x; 1.0547x over previous
//
#include <hip/hip_runtime.h>

// x     [B=32, I=64, K=8192]        f32
// U_in  [I=64, R=8,  K=8192, H=4]   f32  -> float4 per (i,r,k)
// M     [R=8,  S=8,  K=8192, H=4]   f32
// U_out [O=64, S=8,  K=8192, H=4]   f32
// out   [B=32, O=64, K=8192]        f32
//
// Round 11: h-split. Thread = (kk, hp, bs): 16 kk x 2 hp x 16 bs = 512 thr;
// handles 2 b (bs, bs+16) and 2 of 4 h (hp selects float2 of each float4).
// Weight reads become ds_read_b64 (8 B) feeding 4 FMAs (2b x 2h): same
// 64 reads/phase as R5 but HALF the LDS return bytes (R5's measured wall).
// Accumulators stay float2 -> rl+rh=32, sl+sh=32 (b-sequential, fenced)
// -> peak ~55 live regs, fits the 64-VGPR residency envelope ((512,4),
// 2 blocks/CU = 16 waves). h is diagonal through stages 1-2; stage 3 sums
// h via one shfl_xor(16) per output. x shared between hp partners via
// shfl_xor(16) (hp0 loads b_lo's x, hp1 loads b_hi's).
// Staging / x / store counts and vmcnt schedule = R5/R9 verbatim.

static constexpr int IN_CH  = 64;
static constexpr int OUT_CH = 64;
static constexpr int RANK   = 8;
static constexpr int MODES  = 8192;
static constexpr int KT     = 16;            // k per block
static constexpr int CROWS  = 64;            // rows per chunk
static constexpr int CF4    = CROWS * KT;    // 1024 float4 = 16 KB per chunk

typedef const __attribute__((address_space(1))) void* gas_t;
typedef __attribute__((address_space(3))) void* las_t;

#define FENCE asm volatile("" ::: "memory")

// 8-wave staging: wave w loads rows [8w, 8w+8) of a [64 rows][16 kk] float4
// chunk with 2 global_load_lds_dwordx4 (1 KB each; wave-uniform LDS base).
__device__ __forceinline__ void stage_chunk8(const float4* gbase, float4* lbuf,
                                             int wid, int lane) {
    const int sub = lane >> 4;       // 0..3 row within quad
    const int col = lane & 15;       // 0..15 kk
#pragma unroll
    for (int j = 0; j < 2; ++j) {
        const int row0 = wid * 8 + j * 4;                        // wave-uniform
        const float4* src = gbase + (size_t)(row0 + sub) * MODES + col;
        float4* dst = lbuf + row0 * KT;                          // wave-uniform
        __builtin_amdgcn_global_load_lds((gas_t)src, (las_t)dst, 16, 0, 0);
    }
}

__global__ __launch_bounds__(512, 4) void diag_lr_fused(
    const float*  __restrict__ x,
    const float4* __restrict__ Uin,
    const float4* __restrict__ Mw,
    const float4* __restrict__ Uout,
    float*        __restrict__ out)
{
    __shared__ float4 lds[4][CF4];   // 64 KB ring

    const int t    = threadIdx.x;
    const int kk   = t & 15;
    const int hp   = (t >> 4) & 1;   // h-pair: 0 -> h{0,1}, 1 -> h{2,3}
    const int bs   = t >> 5;         // 0..15 ; handles b=bs and b=bs+16
    const int lane = t & 63;
    const int wid  = t >> 6;         // 0..7
    const int k0   = blockIdx.x * KT;
    const int k    = k0 + kk;
    const int myb  = hp ? (bs + 16) : bs;   // the b whose x/out this lane owns

    const float4* UinB = Uin  + k0;  // row p -> + p*MODES
    const float4* MB   = Mw   + k0;
    const float4* UoB  = Uout + k0;
    const float*  xp = x   + (size_t)myb * (IN_CH  * MODES) + k;
    float*        op = out + (size_t)myb * (OUT_CH * MODES) + k;

#define CHUNK_PTR(cc) ((cc) < 8 ? (UinB + (size_t)(cc) * CROWS * MODES) \
                     : (cc) == 8 ? MB \
                     : (UoB + (size_t)((cc) - 9) * CROWS * MODES))

    float xa[2][8];                  // x double buffer (my b only)

    // ---- prologue: queue order [s0(2), x0(8), s1(2)] ----
    stage_chunk8(CHUNK_PTR(0), &lds[0][0], wid, lane);
    FENCE;
#pragma unroll
    for (int ii = 0; ii < 8; ++ii) xa[0][ii] = xp[ii * MODES];
    FENCE;
    stage_chunk8(CHUNK_PTR(1), &lds[1][0], wid, lane);
    FENCE;

    float2 rl[RANK], rh[RANK];       // r for b_lo / b_hi, my 2 h
#pragma unroll
    for (int r = 0; r < RANK; ++r) {
        rl[r] = make_float2(0.f, 0.f);
        rh[r] = make_float2(0.f, 0.f);
    }

    // ---- phases 0..7: U_in ----
#pragma unroll
    for (int c = 0; c < 8; ++c) {
        asm volatile("s_waitcnt vmcnt(2)" ::: "memory");  // s(c), x(c) landed
        __builtin_amdgcn_s_barrier();
        FENCE;
        if (c < 7) {                                      // x(c+1) first,
#pragma unroll
            for (int ii = 0; ii < 8; ++ii)
                xa[(c + 1) & 1][ii] = xp[((c + 1) * 8 + ii) * MODES];
            FENCE;
        }
        stage_chunk8(CHUNK_PTR(c + 2), &lds[(c + 2) & 3][0], wid, lane); // then stage
        FENCE;
        const float2* Lb2 = (const float2*)&lds[c & 3][0];
#pragma unroll
        for (int ii = 0; ii < 8; ++ii) {
            const float myx = xa[c & 1][ii];
            const float ox  = __shfl_xor(myx, 16);        // partner's b
            const float xlo = hp ? ox : myx;
            const float xhi = hp ? myx : ox;
#pragma unroll
            for (int r = 0; r < RANK; ++r) {
                const float2 w = Lb2[((ii * 8 + r) * KT + kk) * 2 + hp];
                rl[r].x = fmaf(w.x, xlo, rl[r].x);
                rl[r].y = fmaf(w.y, xlo, rl[r].y);
                rh[r].x = fmaf(w.x, xhi, rh[r].x);
                rh[r].y = fmaf(w.y, xhi, rh[r].y);
            }
        }
        FENCE;
    }

    // ---- phase 8: M (lds[0]); b-sequential to cap live regs ----
    float2 sl[RANK], sh[RANK];
    {
        asm volatile("s_waitcnt vmcnt(2)" ::: "memory");  // s8 landed, keep s9
        __builtin_amdgcn_s_barrier();
        FENCE;
        stage_chunk8(CHUNK_PTR(10), &lds[10 & 3][0], wid, lane);
        FENCE;
        const float2* Lb2 = (const float2*)&lds[8 & 3][0];
#pragma unroll
        for (int s = 0; s < RANK; ++s) sl[s] = make_float2(0.f, 0.f);
#pragma unroll
        for (int r = 0; r < RANK; ++r)
#pragma unroll
            for (int s = 0; s < RANK; ++s) {
                const float2 w = Lb2[((r * 8 + s) * KT + kk) * 2 + hp];
                sl[s].x = fmaf(w.x, rl[r].x, sl[s].x);
                sl[s].y = fmaf(w.y, rl[r].y, sl[s].y);
            }
        FENCE;  // block CSE-merge of the two M loops (r0 dies before sh builds)
#pragma unroll
        for (int s = 0; s < RANK; ++s) sh[s] = make_float2(0.f, 0.f);
#pragma unroll
        for (int r = 0; r < RANK; ++r)
#pragma unroll
            for (int s = 0; s < RANK; ++s) {
                const float2 w = Lb2[((r * 8 + s) * KT + kk) * 2 + hp];
                sh[s].x = fmaf(w.x, rh[r].x, sh[s].x);
                sh[s].y = fmaf(w.y, rh[r].y, sh[s].y);
            }
        FENCE;
    }

    // ---- phases 9..16: U_out (h-sum via shfl_xor(16); hp selects stored b) ----
#pragma unroll
    for (int c = 9; c < 17; ++c) {
        // queue at wait (instr units): ph9 [s9,s10]->keep 2; ph10 [s10,s11,st9]
        // ->keep 10; ph11-15 [s(c),st(c-2),s(c+1),st(c-1)]->keep 18;
        // ph16 [st13,s16,st14,st15]->keep 16.   (stores = 8/phase)
        if      (c == 9)  asm volatile("s_waitcnt vmcnt(2)"  ::: "memory");
        else if (c == 10) asm volatile("s_waitcnt vmcnt(10)" ::: "memory");
        else if (c == 16) asm volatile("s_waitcnt vmcnt(16)" ::: "memory");
        else              asm volatile("s_waitcnt vmcnt(18)" ::: "memory");
        __builtin_amdgcn_s_barrier();
        FENCE;
        if (c + 2 <= 16) {
            stage_chunk8(CHUNK_PTR(c + 2), &lds[(c + 2) & 3][0], wid, lane);
            FENCE;
        }
        const float2* Lb2 = (const float2*)&lds[c & 3][0];
        const int oc = c - 9;
#pragma unroll
        for (int oo = 0; oo < 8; ++oo) {
            float2 pl = make_float2(0.f, 0.f);
            float2 ph = make_float2(0.f, 0.f);
#pragma unroll
            for (int s = 0; s < RANK; ++s) {
                const float2 w = Lb2[((oo * 8 + s) * KT + kk) * 2 + hp];
                pl.x = fmaf(w.x, sl[s].x, pl.x);
                pl.y = fmaf(w.y, sl[s].y, pl.y);
                ph.x = fmaf(w.x, sh[s].x, ph.x);
                ph.y = fmaf(w.y, sh[s].y, ph.y);
            }
            float fl = pl.x + pl.y;                      // my 2h, b_lo
            float fh = ph.x + ph.y;                      // my 2h, b_hi
            fl += __shfl_xor(fl, 16);                    // + partner's 2h
            fh += __shfl_xor(fh, 16);
            op[(oc * 8 + oo) * MODES] = hp ? fh : fl;    // hp0->b_lo, hp1->b_hi
        }
        FENCE;
    }
#undef CHUNK_PTR
}

extern "C" void kernel_launch(void* const* d_in, const int* in_sizes, int n_in,
                              void* d_out, int out_size, void* d_ws, size_t ws_size,
                              hipStream_t stream) {
    const float*  x    = (const float*)d_in[0];
    const float4* Uin  = (const float4*)d_in[1];
    const float4* Mw   = (const float4*)d_in[2];
    const float4* Uout = (const float4*)d_in[3];
    float* out = (float*)d_out;

    dim3 grid(512), block(512);
    hipLaunchKernelGGL(diag_lr_fused, grid, block, 0, stream, x, Uin, Mw, Uout, out);
}

// Round 12
// 82.804 us; speedup vs baseline: 1.1987x; 1.1365x over previous
//
#include <hip/hip_runtime.h>

// x     [B=32, I=64, K=8192]        f32
// U_in  [I=64, R=8,  K=8192, H=4]   f32  -> float4 per (i,r,k)
// M     [R=8,  S=8,  K=8192, H=4]   f32
// U_out [O=64, S=8,  K=8192, H=4]   f32
// out   [B=32, O=64, K=8192]        f32
//
// Round 12: occupancy-max probe. Block = 1024 thr = 16 kk x 2 rowhalf x 32 b
// (1 b/thread), grid 512 -> 2 blocks/CU x 16 waves = 32 waves/CU (2x R5).
// Row-half split keeps all reads ds_read_b128 in the R6-proven conflict-free
// pattern (2 addrs/bank). Register budget engineered <= ~56 (64-cap tier):
//   stage1: partial r over my 4-of-8 i-rows (racc 32) -> shfl_xor(16) reduce
//   stage2: my 4-of-8 s from full r (sh2 16) -> exchange via shfl + cndmask
//           (STATIC indices only) -> full s (sf 32), racc dead
//   stage3: my 4-of-8 o per chunk from full s; no per-phase shuffles
// R=4 LDS ring (64 KB), staged 2 ahead via global_load_lds (1 instr/wave),
// ONE barrier/phase, counted vmcnt (stage=1, x=4, stores=4 per wave).

static constexpr int IN_CH  = 64;
static constexpr int OUT_CH = 64;
static constexpr int RANK   = 8;
static constexpr int MODES  = 8192;
static constexpr int KT     = 16;            // k per block
static constexpr int CROWS  = 64;            // rows per chunk
static constexpr int CF4    = CROWS * KT;    // 1024 float4 = 16 KB per chunk

typedef const __attribute__((address_space(1))) void* gas_t;
typedef __attribute__((address_space(3))) void* las_t;

#define FENCE asm volatile("" ::: "memory")

__device__ __forceinline__ void fma_s4(float4& a, const float4 w, const float v) {
    a.x = fmaf(w.x, v, a.x); a.y = fmaf(w.y, v, a.y);
    a.z = fmaf(w.z, v, a.z); a.w = fmaf(w.w, v, a.w);
}
__device__ __forceinline__ void fma_44(float4& a, const float4 w, const float4 v) {
    a.x = fmaf(w.x, v.x, a.x); a.y = fmaf(w.y, v.y, a.y);
    a.z = fmaf(w.z, v.z, a.z); a.w = fmaf(w.w, v.w, a.w);
}

// 16-wave staging: wave w loads rows [4w, 4w+4) of a [64 rows][16 kk] float4
// chunk with ONE global_load_lds_dwordx4 (1 KB; wave-uniform LDS base).
__device__ __forceinline__ void stage_chunk16(const float4* gbase, float4* lbuf,
                                              int wid, int lane) {
    const int sub = lane >> 4;       // 0..3 row within quad
    const int col = lane & 15;       // 0..15 kk
    const float4* src = gbase + (size_t)(wid * 4 + sub) * MODES + col;
    float4* dst = lbuf + wid * 4 * KT;                           // wave-uniform
    __builtin_amdgcn_global_load_lds((gas_t)src, (las_t)dst, 16, 0, 0);
}

__global__ __launch_bounds__(1024, 2) void diag_lr_fused(
    const float*  __restrict__ x,
    const float4* __restrict__ Uin,
    const float4* __restrict__ Mw,
    const float4* __restrict__ Uout,
    float*        __restrict__ out)
{
    __shared__ float4 lds[4][CF4];   // 64 KB ring

    const int t    = threadIdx.x;
    const int kk   = t & 15;
    const int half = (t >> 4) & 1;   // row-half within each chunk (lane bit 4)
    const int b    = t >> 5;         // 0..31 (one b per thread)
    const int lane = t & 63;
    const int wid  = t >> 6;         // 0..15
    const int k0   = blockIdx.x * KT;
    const int k    = k0 + kk;
    const int h4   = half * 4;       // first local row (ii / ss / oo) of my half

    const float4* UinB = Uin  + k0;  // row p -> + p*MODES
    const float4* MB   = Mw   + k0;
    const float4* UoB  = Uout + k0;
    const float*  xp = x   + (size_t)b * (IN_CH  * MODES) + k;
    float*        op = out + (size_t)b * (OUT_CH * MODES) + k;

#define CHUNK_PTR(cc) ((cc) < 8 ? (UinB + (size_t)(cc) * CROWS * MODES) \
                     : (cc) == 8 ? MB \
                     : (UoB + (size_t)((cc) - 9) * CROWS * MODES))

    float xa[2][4];                  // x double buffer (my half's 4 i-rows)

    // ---- prologue: queue order [s0(1), x0(4), s1(1)] ----
    stage_chunk16(CHUNK_PTR(0), &lds[0][0], wid, lane);
    FENCE;
#pragma unroll
    for (int ii = 0; ii < 4; ++ii) xa[0][ii] = xp[(h4 + ii) * MODES];
    FENCE;
    stage_chunk16(CHUNK_PTR(1), &lds[1][0], wid, lane);
    FENCE;

    float4 racc[RANK];               // PARTIAL r (my ii-half only)
#pragma unroll
    for (int r = 0; r < RANK; ++r) racc[r] = make_float4(0.f, 0.f, 0.f, 0.f);

    // ---- phases 0..7: U_in (my half's 4 of 8 i-rows) ----
#pragma unroll
    for (int c = 0; c < 8; ++c) {
        asm volatile("s_waitcnt vmcnt(1)" ::: "memory");  // s(c), x(c) landed
        __builtin_amdgcn_s_barrier();
        FENCE;
        if (c < 7) {                                      // x(c+1) first,
#pragma unroll
            for (int ii = 0; ii < 4; ++ii)
                xa[(c + 1) & 1][ii] = xp[((c + 1) * 8 + h4 + ii) * MODES];
            FENCE;
        }
        stage_chunk16(CHUNK_PTR(c + 2), &lds[(c + 2) & 3][0], wid, lane); // then stage
        FENCE;
        const float4* Lb = &lds[c & 3][0];
#pragma unroll
        for (int ii = 0; ii < 4; ++ii) {
            const float xv = xa[c & 1][ii];
#pragma unroll
            for (int r = 0; r < RANK; ++r)
                fma_s4(racc[r], Lb[((h4 + ii) * 8 + r) * KT + kk], xv);
        }
        FENCE;
    }

    // ---- cross-half i-reduction: pair lane = lane ^ 16 (same kk, same b) ----
#pragma unroll
    for (int r = 0; r < RANK; ++r) {
        racc[r].x += __shfl_xor(racc[r].x, 16);
        racc[r].y += __shfl_xor(racc[r].y, 16);
        racc[r].z += __shfl_xor(racc[r].z, 16);
        racc[r].w += __shfl_xor(racc[r].w, 16);
    }

    // ---- phase 8: M (lds[0]); my 4-of-8 s from full r ----
    float4 sh2[4];
#pragma unroll
    for (int ss = 0; ss < 4; ++ss) sh2[ss] = make_float4(0.f, 0.f, 0.f, 0.f);
    {
        asm volatile("s_waitcnt vmcnt(1)" ::: "memory");  // s8 landed, keep s9
        __builtin_amdgcn_s_barrier();
        FENCE;
        stage_chunk16(CHUNK_PTR(10), &lds[10 & 3][0], wid, lane);
        FENCE;
        const float4* Lb = &lds[8 & 3][0];
#pragma unroll
        for (int r = 0; r < RANK; ++r)
#pragma unroll
            for (int ss = 0; ss < 4; ++ss)
                fma_44(sh2[ss], Lb[(r * 8 + h4 + ss) * KT + kk], racc[r]);
        FENCE;
    }

    // ---- exchange s halves -> full s (STATIC indices; cndmask select) ----
    float4 sf[RANK];
#pragma unroll
    for (int ss = 0; ss < 4; ++ss) {
        const float4 mine = sh2[ss];
        float4 oth;
        oth.x = __shfl_xor(mine.x, 16);
        oth.y = __shfl_xor(mine.y, 16);
        oth.z = __shfl_xor(mine.z, 16);
        oth.w = __shfl_xor(mine.w, 16);
        sf[ss]     = half ? oth  : mine;   // s index ss   belongs to half 0
        sf[ss + 4] = half ? mine : oth;    // s index ss+4 belongs to half 1
    }

    // ---- phases 9..16: U_out (my half's 4 of 8 o per chunk, full s) ----
#pragma unroll
    for (int c = 9; c < 17; ++c) {
        // per-wave vmcnt units: stage=1, x=4, stores=4.
        // ph9 queue [s9,s10] -> keep 1; ph10 [s10,s11,st9(4)] -> keep 5;
        // ph11-15 [s(c),st(c-2)(4),s(c+1),st(c-1)(4)] -> keep 9;
        // ph16 [s16,st14(4),st15(4)] -> keep 8.
        if      (c == 9)  asm volatile("s_waitcnt vmcnt(1)" ::: "memory");
        else if (c == 10) asm volatile("s_waitcnt vmcnt(5)" ::: "memory");
        else if (c == 16) asm volatile("s_waitcnt vmcnt(8)" ::: "memory");
        else              asm volatile("s_waitcnt vmcnt(9)" ::: "memory");
        __builtin_amdgcn_s_barrier();
        FENCE;
        if (c + 2 <= 16) {
            stage_chunk16(CHUNK_PTR(c + 2), &lds[(c + 2) & 3][0], wid, lane);
            FENCE;
        }
        const float4* Lb = &lds[c & 3][0];
        const int oc = c - 9;
#pragma unroll
        for (int j = 0; j < 4; ++j) {
            float4 a = make_float4(0.f, 0.f, 0.f, 0.f);
#pragma unroll
            for (int ss = 0; ss < RANK; ++ss)
                fma_44(a, Lb[((h4 + j) * 8 + ss) * KT + kk], sf[ss]);
            op[(oc * 8 + h4 + j) * MODES] = (a.x + a.y) + (a.z + a.w);
        }
        FENCE;
    }
#undef CHUNK_PTR
}

extern "C" void kernel_launch(void* const* d_in, const int* in_sizes, int n_in,
                              void* d_out, int out_size, void* d_ws, size_t ws_size,
                              hipStream_t stream) {
    const float*  x    = (const float*)d_in[0];
    const float4* Uin  = (const float4*)d_in[1];
    const float4* Mw   = (const float4*)d_in[2];
    const float4* Uout = (const float4*)d_in[3];
    float* out = (float*)d_out;

    dim3 grid(512), block(1024);
    hipLaunchKernelGGL(diag_lr_fused, grid, block, 0, stream, x, Uin, Mw, Uout, out);
}

// Round 13
// 82.394 us; speedup vs baseline: 1.2047x; 1.0050x over previous
//
#include <hip/hip_runtime.h>

// x     [B=32, I=64, K=8192]        f32
// U_in  [I=64, R=8,  K=8192, H=4]   f32
// M     [R=8,  S=8,  K=8192, H=4]   f32
// U_out [O=64, S=8,  K=8192, H=4]   f32
// out   [B=32, O=64, K=8192]        f32
//
// Round 13 = R11 compute structure (512 thr = 16 kk x 2 hp x 16 bs, 2 b and
// 2 h per thread, ds_read_b64 weights = half of R5's LDS return bytes, VGPR
// ~64 -> 16 waves/CU) with the bank conflicts fixed:
//   LDS chunk layout h-SPLIT: region[hp][64 row][16 kk] float2, regions 8KB
//   apart. Lane dword = hp*2048+row*32+2kk -> banks {2kk,2kk+1}: all 32
//   banks, exactly 2 addrs/bank (minimal; free per m136). R11's layout hit
//   16 banks at 4 addrs/bank (1.9e7 conflicts) -> that was the regression.
//   Split layout staged via size-4 global_load_lds with pre-permuted
//   per-lane SOURCE addresses (linear LDS dest, m173 pattern).
// R=4 ring (64 KB), staged 2 ahead, ONE barrier/phase, counted vmcnt
// (per-wave units: stage=8, x=8, stores=8 -> 0-9:8, 10:16, 11-15:24, 16:16).

static constexpr int IN_CH  = 64;
static constexpr int OUT_CH = 64;
static constexpr int RANK   = 8;
static constexpr int MODES  = 8192;
static constexpr int KT     = 16;            // k per block
static constexpr int CROWS  = 64;            // rows per chunk
static constexpr int CDW    = 4096;          // dwords per chunk (16 KB)

typedef const __attribute__((address_space(1))) void* gas_t;
typedef __attribute__((address_space(3))) void* las_t;

#define FENCE asm volatile("" ::: "memory")

// Stage one 16 KB chunk into the h-split layout:
// new-layout dword n = ((hp*64+row)*16+kk)*2+hl  (hp=h>>1, hl=h&1)
// instruction j (0..63, wave-uniform) writes LDS dwords [64j, 64j+64) at
// dst = lbuf + 64j + lane*4B (linear); per-lane source dword =
//   Aoff + (j&31)*8*MODES + (j>>5)*2,  Aoff = (lane>>5)*4*MODES
//                                            + ((lane>>1)&15)*4 + (lane&1).
// (verified: row5,kk3,h2 -> n=2214=64*34+38, src dword 163854 = global ✓)
__device__ __forceinline__ void stage_chunk_split(const float4* gbase, float* lbuf,
                                                  int wid, int Aoff) {
    const float* gf = (const float*)gbase;
#pragma unroll
    for (int jj = 0; jj < 8; ++jj) {
        const int j  = wid * 8 + jj;            // wave-uniform
        const int jq = j & 31;
        const int hp = j >> 5;
        const float* src = gf + Aoff + jq * (8 * MODES) + hp * 2;
        float* dst = lbuf + j * 64;             // wave-uniform
        __builtin_amdgcn_global_load_lds((gas_t)src, (las_t)dst, 4, 0, 0);
    }
}

__global__ __launch_bounds__(512, 4) void diag_lr_fused(
    const float*  __restrict__ x,
    const float4* __restrict__ Uin,
    const float4* __restrict__ Mw,
    const float4* __restrict__ Uout,
    float*        __restrict__ out)
{
    __shared__ float lds[4][CDW];    // 64 KB ring, h-split chunks

    const int t    = threadIdx.x;
    const int kk   = t & 15;
    const int hp   = (t >> 4) & 1;   // h-pair: 0 -> h{0,1}, 1 -> h{2,3}
    const int bs   = t >> 5;         // 0..15 ; handles b=bs and b=bs+16
    const int lane = t & 63;
    const int wid  = t >> 6;         // 0..7
    const int k0   = blockIdx.x * KT;
    const int k    = k0 + kk;
    const int myb  = hp ? (bs + 16) : bs;   // the b whose x/out this lane owns

    // staging source permutation constants (dwords)
    const int Aoff = ((lane >> 5) & 1) * (4 * MODES)
                   + ((lane >> 1) & 15) * 4 + (lane & 1);

    const float4* UinB = Uin  + k0;  // row p -> + p*MODES (float4 units)
    const float4* MB   = Mw   + k0;
    const float4* UoB  = Uout + k0;
    const float*  xp = x   + (size_t)myb * (IN_CH  * MODES) + k;
    float*        op = out + (size_t)myb * (OUT_CH * MODES) + k;

#define CHUNK_PTR(cc) ((cc) < 8 ? (UinB + (size_t)(cc) * CROWS * MODES) \
                     : (cc) == 8 ? MB \
                     : (UoB + (size_t)((cc) - 9) * CROWS * MODES))

    // per-thread read base within a chunk (float2 units): region + kk
    const int rbase = hp * 1024 + kk;

    float xa[2][8];                  // x double buffer (my b only)

    // ---- prologue: queue order [s0(8), x0(8), s1(8)] ----
    stage_chunk_split(CHUNK_PTR(0), &lds[0][0], wid, Aoff);
    FENCE;
#pragma unroll
    for (int ii = 0; ii < 8; ++ii) xa[0][ii] = xp[ii * MODES];
    FENCE;
    stage_chunk_split(CHUNK_PTR(1), &lds[1][0], wid, Aoff);
    FENCE;

    float2 rl[RANK], rh[RANK];       // r for b_lo / b_hi, my 2 h
#pragma unroll
    for (int r = 0; r < RANK; ++r) {
        rl[r] = make_float2(0.f, 0.f);
        rh[r] = make_float2(0.f, 0.f);
    }

    // ---- phases 0..7: U_in (rows ii*8+r) ----
#pragma unroll
    for (int c = 0; c < 8; ++c) {
        asm volatile("s_waitcnt vmcnt(8)" ::: "memory");  // s(c), x(c) landed
        __builtin_amdgcn_s_barrier();
        FENCE;
        if (c < 7) {                                      // x(c+1) first,
#pragma unroll
            for (int ii = 0; ii < 8; ++ii)
                xa[(c + 1) & 1][ii] = xp[((c + 1) * 8 + ii) * MODES];
            FENCE;
        }
        stage_chunk_split(CHUNK_PTR(c + 2), &lds[(c + 2) & 3][0], wid, Aoff);
        FENCE;
        const float2* Rb = (const float2*)&lds[c & 3][0] + rbase;
#pragma unroll
        for (int ii = 0; ii < 8; ++ii) {
            const float myx = xa[c & 1][ii];
            const float ox  = __shfl_xor(myx, 16);        // partner's b
            const float xlo = hp ? ox : myx;
            const float xhi = hp ? myx : ox;
#pragma unroll
            for (int r = 0; r < RANK; ++r) {
                const float2 w = Rb[(ii * 8 + r) * 16];
                rl[r].x = fmaf(w.x, xlo, rl[r].x);
                rl[r].y = fmaf(w.y, xlo, rl[r].y);
                rh[r].x = fmaf(w.x, xhi, rh[r].x);
                rh[r].y = fmaf(w.y, xhi, rh[r].y);
            }
        }
        FENCE;
    }

    // ---- phase 8: M (ring slot 0); b-sequential to cap live regs ----
    float2 sl[RANK], sh[RANK];
    {
        asm volatile("s_waitcnt vmcnt(8)" ::: "memory");  // s8 landed, keep s9
        __builtin_amdgcn_s_barrier();
        FENCE;
        stage_chunk_split(CHUNK_PTR(10), &lds[10 & 3][0], wid, Aoff);
        FENCE;
        const float2* Rb = (const float2*)&lds[8 & 3][0] + rbase;
#pragma unroll
        for (int s = 0; s < RANK; ++s) sl[s] = make_float2(0.f, 0.f);
#pragma unroll
        for (int r = 0; r < RANK; ++r)
#pragma unroll
            for (int s = 0; s < RANK; ++s) {
                const float2 w = Rb[(r * 8 + s) * 16];
                sl[s].x = fmaf(w.x, rl[r].x, sl[s].x);
                sl[s].y = fmaf(w.y, rl[r].y, sl[s].y);
            }
        FENCE;  // block CSE-merge (rl dies before sh builds)
#pragma unroll
        for (int s = 0; s < RANK; ++s) sh[s] = make_float2(0.f, 0.f);
#pragma unroll
        for (int r = 0; r < RANK; ++r)
#pragma unroll
            for (int s = 0; s < RANK; ++s) {
                const float2 w = Rb[(r * 8 + s) * 16];
                sh[s].x = fmaf(w.x, rh[r].x, sh[s].x);
                sh[s].y = fmaf(w.y, rh[r].y, sh[s].y);
            }
        FENCE;
    }

    // ---- phases 9..16: U_out (rows oo*8+s; h-sum via shfl_xor(16)) ----
#pragma unroll
    for (int c = 9; c < 17; ++c) {
        // per-wave vmcnt units: stage=8, x=8, stores=8 (derived in header)
        if      (c == 9)  asm volatile("s_waitcnt vmcnt(8)"  ::: "memory");
        else if (c == 10) asm volatile("s_waitcnt vmcnt(16)" ::: "memory");
        else if (c == 16) asm volatile("s_waitcnt vmcnt(16)" ::: "memory");
        else              asm volatile("s_waitcnt vmcnt(24)" ::: "memory");
        __builtin_amdgcn_s_barrier();
        FENCE;
        if (c + 2 <= 16) {
            stage_chunk_split(CHUNK_PTR(c + 2), &lds[(c + 2) & 3][0], wid, Aoff);
            FENCE;
        }
        const float2* Rb = (const float2*)&lds[c & 3][0] + rbase;
        const int oc = c - 9;
#pragma unroll
        for (int oo = 0; oo < 8; ++oo) {
            float2 pl = make_float2(0.f, 0.f);
            float2 ph = make_float2(0.f, 0.f);
#pragma unroll
            for (int s = 0; s < RANK; ++s) {
                const float2 w = Rb[(oo * 8 + s) * 16];
                pl.x = fmaf(w.x, sl[s].x, pl.x);
                pl.y = fmaf(w.y, sl[s].y, pl.y);
                ph.x = fmaf(w.x, sh[s].x, ph.x);
                ph.y = fmaf(w.y, sh[s].y, ph.y);
            }
            float fl = pl.x + pl.y;                      // my 2h, b_lo
            float fh = ph.x + ph.y;                      // my 2h, b_hi
            fl += __shfl_xor(fl, 16);                    // + partner's 2h
            fh += __shfl_xor(fh, 16);
            op[(oc * 8 + oo) * MODES] = hp ? fh : fl;    // hp0->b_lo, hp1->b_hi
        }
        FENCE;
    }
#undef CHUNK_PTR
}

extern "C" void kernel_launch(void* const* d_in, const int* in_sizes, int n_in,
                              void* d_out, int out_size, void* d_ws, size_t ws_size,
                              hipStream_t stream) {
    const float*  x    = (const float*)d_in[0];
    const float4* Uin  = (const float4*)d_in[1];
    const float4* Mw   = (const float4*)d_in[2];
    const float4* Uout = (const float4*)d_in[3];
    float* out = (float*)d_out;

    dim3 grid(512), block(512);
    hipLaunchKernelGGL(diag_lr_fused, grid, block, 0, stream, x, Uin, Mw, Uout, out);
}